// Round 15
// baseline (60.937 us; speedup 1.0000x reference)
//
#include <hip/hip_runtime.h>
#include <cstdint>

static constexpr int BATCH = 64;
static constexpr int NPB   = 512 * 512;   // elements per batch
static constexpr int NFB   = 2048;        // fine fixed bins in sigmoid space [0,1]
static constexpr int PBLK  = 16;          // blocks per batch (1024 total)
static constexpr int ELB   = NPB / PBLK;  // 16384 elements per block

// d_ws layout in 32-bit words (~4.3 MB):
static constexpr int W_BMIN = 0;      // 1024 blocks x 4 waves = 4096 floats
static constexpr int W_BMAX = 4096;   // 4096 floats
static constexpr int W_T1   = 8192;   // 64 tickets, 32-word (128 B) stride
static constexpr int W_T2   = 10240;  // 64 tickets, 32-word stride
static constexpr int W_J    = 12288;  // 64 J words, 32-word stride (sentinel 0xFFFFFFFF)
static constexpr int W_CNT  = 14336;  // nb[64], nt[64], ni[64]
static constexpr int W_PART = 14592;  // 1024 x 1024 words (u16-packed fine hist pairs)

__device__ __forceinline__ float sigmoidf(float v) {  // precise: pmin/pmax only
  if (v >= 0.0f) return 1.0f / (1.0f + expf(-v));
  float e = expf(v);
  return e / (1.0f + e);
}
__device__ __forceinline__ float fsig(float v) {      // fast: per-element binning only
  return __builtin_amdgcn_rcpf(1.0f + __expf(-v));
}
__device__ __forceinline__ uint32_t llc_load(const uint32_t* p) {   // served at LLC
  return __hip_atomic_load(p, __ATOMIC_RELAXED, __HIP_MEMORY_SCOPE_SYSTEM);
}
__device__ __forceinline__ float llc_loadf(const float* p) {
  return __hip_atomic_load(p, __ATOMIC_RELAXED, __HIP_MEMORY_SCOPE_SYSTEM);
}
__device__ __forceinline__ void llc_store(uint32_t* p, uint32_t v) {  // write-through
  __hip_atomic_store(p, v, __ATOMIC_RELAXED, __HIP_MEMORY_SCOPE_SYSTEM);
}
__device__ __forceinline__ void llc_storef(float* p, float v) {
  __hip_atomic_store(p, v, __ATOMIC_RELAXED, __HIP_MEMORY_SCOPE_SYSTEM);
}

// Init: tickets/J/counters/out. Covers words [W_T1, W_CNT+192) = 6336 words.
__global__ __launch_bounds__(256) void k_init(uint32_t* __restrict__ ws,
                                              float* __restrict__ out) {
  const int i = blockIdx.x * 256 + threadIdx.x;
  const int w = W_T1 + i;
  if (w < W_CNT + 192) ws[w] = (w >= W_J && w < W_CNT) ? 0xFFFFFFFFu : 0u;
  if (i == 0) out[0] = 0.0f;
}

// Fused single-stream kernel. 1024 blocks x 256 thr; ~25.2 KiB LDS -> 6 blocks/CU
// -> 1536 slots >= 1024: ALL blocks co-resident (spin deadlock-free by capacity).
__global__ __launch_bounds__(256, 6) void k_main(const float* __restrict__ x,
                                                 const float* __restrict__ tg,
                                                 uint32_t* __restrict__ ws,
                                                 float* __restrict__ out) {
  __shared__ uint32_t smem[6400];        // pool: c8[4096] | hist[2048] | h256[256]
  uint32_t* c8   = smem;                 // 16 KiB: 8-bit codes, 4 packed per u32
  uint32_t* hist = smem + 4096;          // 8 KiB: subsample hist -> tot -> scan scratch
  uint32_t* h256 = smem + 6144;          // 1 KiB: 256-bin Otsu hist
  // scan scratch aliases hist AFTER tot is dead (post-remap):
  uint32_t* scanA = hist;                          // w1 scan
  float*    scanB = reinterpret_cast<float*>(hist + 256);
  float*    scanC = reinterpret_cast<float*>(hist + 512);
  int*      scanD = reinterpret_cast<int*>(hist + 768);
  __shared__ unsigned long long sw[4];
  __shared__ uint32_t sJ;
  __shared__ int sFlag;
  __shared__ float sPmin, sScale, sBinw;
  const int t = threadIdx.x, g = blockIdx.x;
  const int b = g >> 4, blk = g & 15;
  float* wsf = reinterpret_cast<float*>(ws);

#pragma unroll
  for (int q = 0; q < 2; ++q)
    reinterpret_cast<uint4*>(hist)[t + q * 256] = uint4{0u, 0u, 0u, 0u};
  __syncthreads();

  const size_t base = (size_t)b * NPB + (size_t)blk * ELB;
  const float4* px = reinterpret_cast<const float4*>(x + base);
  const float4* pt = reinterpret_cast<const float4*>(tg + base);

  // ---- phase 1: ONE stream. codes->LDS, tmask->VGPR, min/max, 1/4-sub hist ----
  uint32_t tmask[2];
  float mn = INFINITY, mx = -INFINITY;
#pragma unroll
  for (int o = 0; o < 2; ++o) {
    uint32_t tm = 0u;
#pragma unroll
    for (int ii = 0; ii < 8; ++ii) {
      const int i = o * 8 + ii;
      float4 v = px[i * 256 + t];
      float4 w = pt[i * 256 + t];
      mn = fminf(mn, fminf(fminf(v.x, v.y), fminf(v.z, v.w)));
      mx = fmaxf(mx, fmaxf(fmaxf(v.x, v.y), fmaxf(v.z, v.w)));
      const float f0 = fsig(v.x), f1 = fsig(v.y), f2 = fsig(v.z), f3 = fsig(v.w);
      int i0 = (int)(f0 * 256.0f); i0 = i0 > 255 ? 255 : i0;
      int i1 = (int)(f1 * 256.0f); i1 = i1 > 255 ? 255 : i1;
      int i2 = (int)(f2 * 256.0f); i2 = i2 > 255 ? 255 : i2;
      int i3 = (int)(f3 * 256.0f); i3 = i3 > 255 ? 255 : i3;
      c8[i * 256 + t] = (uint32_t)i0 | ((uint32_t)i1 << 8) |
                        ((uint32_t)i2 << 16) | ((uint32_t)i3 << 24);
      const uint32_t b0 = w.x > 0.5f, b1 = w.y > 0.5f, b2 = w.z > 0.5f, b3 = w.w > 0.5f;
      tm |= (b0 | (b1 << 1) | (b2 << 2) | (b3 << 3)) << (ii * 4);
      if ((ii & 3) == 0) {               // 1/4 subsample -> 2048-bin Otsu hist
#define PUT(f) { int s_ = (int)((f) * 2048.0f); s_ = s_ > 2047 ? 2047 : s_;      \
                 (void)__hip_atomic_fetch_add(&hist[s_], 1u, __ATOMIC_RELAXED,   \
                                              __HIP_MEMORY_SCOPE_WORKGROUP); }
        PUT(f0) PUT(f1) PUT(f2) PUT(f3)
#undef PUT
      }
    }
    tmask[o] = tm;
  }
  for (int off = 32; off; off >>= 1) {
    mn = fminf(mn, __shfl_down(mn, off));
    mx = fmaxf(mx, __shfl_down(mx, off));
  }
  if ((t & 63) == 0) {                   // per-wave min/max -> LLC (write-through)
    llc_storef(&wsf[W_BMIN + g * 4 + (t >> 6)], mn);
    llc_storef(&wsf[W_BMAX + g * 4 + (t >> 6)], mx);
  }
  __syncthreads();                       // hist LDS atomics complete
  // flush u16-packed partial hist (1024 words) via system-scope stores (at LLC)
  uint32_t* gp = ws + W_PART + (size_t)g * (NFB / 2);
#pragma unroll
  for (int q = 0; q < 4; ++q) {
    const int w_ = t + q * 256;          // word 0..1023 -> bins 2w, 2w+1
    llc_store(&gp[w_], hist[2 * w_] | (hist[2 * w_ + 1] << 16));
  }
  __syncthreads();
  if (t == 0) {
    asm volatile("s_waitcnt vmcnt(0)" ::: "memory");   // partials at LLC BEFORE ticket
    const uint32_t old = atomicAdd(&ws[W_T1 + b * 32], 1u);
    sFlag = (old == PBLK - 1);
  }
  __syncthreads();

  // ---- leader (last arriver of the batch): merge -> Otsu -> K8 -> publish J ----
  if (sFlag) {
#pragma unroll
    for (int q = 0; q < 4; ++q) {        // merge 16 u16-packed partials into tot
      const int w_ = t + q * 256;
      uint32_t a0 = 0, a1 = 0;
      for (int p = 0; p < PBLK; ++p) {
        const uint32_t v = llc_load(&ws[W_PART + (size_t)(b * PBLK + p) * (NFB / 2) + w_]);
        a0 += v & 0xFFFFu;
        a1 += v >> 16;
      }
      hist[2 * w_] = a0;
      hist[2 * w_ + 1] = a1;
    }
    h256[t] = 0u;
    float mnv = INFINITY, mxv = -INFINITY;
    if (t < 64) {                        // 16 blocks x 4 waves = 64 values
      mnv = llc_loadf(&wsf[W_BMIN + b * 64 + t]);
      mxv = llc_loadf(&wsf[W_BMAX + b * 64 + t]);
    }
    for (int off = 32; off; off >>= 1) {
      mnv = fminf(mnv, __shfl_down(mnv, off));
      mxv = fmaxf(mxv, __shfl_down(mxv, off));
    }
    if (t == 0) {
      const float pmin = sigmoidf(mnv);
      const float pmax = sigmoidf(mxv);
      const float span = pmax - pmin;
      sPmin = pmin;
      sScale = (span > 0.0f) ? (512.0f / span) : -1.0f;   // negative = degenerate
      sBinw = span * (1.0f / 256.0f);
    }
    __syncthreads();
    const float pmin = sPmin, scale = sScale, binw = sBinw;
    if (scale < 0.0f) {
      if (t == 0) atomicExch(&ws[W_J + b * 32], 256u);    // count none (matches ref)
    } else {
#pragma unroll
      for (int q = 0; q < 8; ++q) {      // fine -> 256-bin via midpoint halfbin map
        const int k = t + q * 256;
        const uint32_t c = hist[k];
        if (c) {
          const float rep = ((float)k + 0.5f) * (1.0f / 2048.0f);
          int ci = (int)((rep - pmin) * scale);
          ci = ci < 0 ? 0 : (ci > 511 ? 511 : ci);
          atomicAdd(&h256[ci >> 1], c);
        }
      }
      __syncthreads();                   // tot now dead; scans may alias hist
      const uint32_t hk = h256[t];
      const float ck = pmin + ((float)t + 0.5f) * binw;   // centers[t]
      scanA[t] = hk;
      scanB[t] = (float)hk * ck;
      for (int off = 1; off < 256; off <<= 1) {           // Hillis-Steele scans
        __syncthreads();
        uint32_t wp = (t >= off) ? scanA[t - off] : 0u;
        float    sp = (t >= off) ? scanB[t - off] : 0.0f;
        __syncthreads();
        scanA[t] += wp; scanB[t] += sp;
      }
      __syncthreads();
      const uint32_t totW = scanA[255];
      const float totS = scanB[255];
      float vv = -INFINITY;
      if (t < 255 && scanA[t] > 0u && totW > scanA[t]) {
        const float w1f = (float)scanA[t];
        const float w2f = (float)(totW - scanA[t]);
        const float m1 = scanB[t] / w1f;
        const float m2 = (totS - scanB[t]) / w2f;
        const float d = m1 - m2;
        vv = (w1f * w2f) * (d * d);
      }
      scanC[t] = vv; scanD[t] = t;
      for (int s = 128; s; s >>= 1) {    // argmax, first-occurrence tie-break
        __syncthreads();
        if (t < s) {
          const float vb = scanC[t + s]; const int ib = scanD[t + s];
          if (vb > scanC[t] || (vb == scanC[t] && ib < scanD[t])) {
            scanC[t] = vb; scanD[t] = ib;
          }
        }
      }
      __syncthreads();
      const int Jh = 2 * scanD[0] + 1;   // halfbin boundary index
      if (t == 0) sJ = 256u;
      __syncthreads();
      {                                  // min code-grid k whose midpoint maps >= Jh
        const float rep = ((float)t + 0.5f) * (1.0f / 256.0f);
        int ci = (int)((rep - pmin) * scale);
        ci = ci < 0 ? 0 : (ci > 511 ? 511 : ci);
        if (ci >= Jh) atomicMin(&sJ, (uint32_t)t);
      }
      __syncthreads();
      if (t == 0) atomicExch(&ws[W_J + b * 32], sJ);
    }
  }

  // ---- all blocks: poll this batch's J at the LLC ----
  if (t == 0) {
    uint32_t jv;
    while ((jv = llc_load(&ws[W_J + b * 32])) == 0xFFFFFFFFu)
      __builtin_amdgcn_s_sleep(16);
    sJ = jv;
  }
  __syncthreads();
  const uint32_t K8 = sJ;

  // ---- count from LDS codes + register tmask (no memory re-read) ----
  uint32_t nb = 0, ni = 0, nt = 0;
#pragma unroll
  for (int o = 0; o < 2; ++o) {
    const uint32_t tm = tmask[o];
    nt += __popc(tm);
#pragma unroll
    for (int ii = 0; ii < 8; ++ii) {
      const int i = o * 8 + ii;
      const uint32_t cw = c8[i * 256 + t];
      const uint32_t m = (tm >> (ii * 4)) & 0xFu;
#pragma unroll
      for (int e = 0; e < 4; ++e) {
        const uint32_t ge = ((cw >> (8 * e)) & 0xFFu) >= K8 ? 1u : 0u;
        nb += ge;
        ni += ge & ((m >> e) & 1u);
      }
    }
  }
  unsigned long long P = (unsigned long long)nb |
                         ((unsigned long long)nt << 20) |
                         ((unsigned long long)ni << 40);
  for (int off = 32; off; off >>= 1) P += __shfl_down(P, off);
  if ((t & 63) == 0) sw[t >> 6] = P;
  __syncthreads();
  if (t == 0) {
    P = sw[0] + sw[1] + sw[2] + sw[3];
    atomicAdd(&ws[W_CNT + b],       (uint32_t)(P & 0xFFFFFu));
    atomicAdd(&ws[W_CNT + 64 + b],  (uint32_t)((P >> 20) & 0xFFFFFu));
    atomicAdd(&ws[W_CNT + 128 + b], (uint32_t)((P >> 40) & 0xFFFFFu));
    asm volatile("s_waitcnt vmcnt(0)" ::: "memory");   // counts at LLC BEFORE ticket
    const uint32_t old = atomicAdd(&ws[W_T2 + b * 32], 1u);
    if (old == PBLK - 1) {               // last block of this batch -> IoU
      const float NB = (float)llc_load(&ws[W_CNT + b]);
      const float NT = (float)llc_load(&ws[W_CNT + 64 + b]);
      const float NI = (float)llc_load(&ws[W_CNT + 128 + b]);
      atomicAdd(out, ((NI + 1.0f) / ((NB + NT - NI) + 1.0f)) * (1.0f / 64.0f));
    }
  }
}

extern "C" void kernel_launch(void* const* d_in, const int* in_sizes, int n_in,
                              void* d_out, int out_size, void* d_ws, size_t ws_size,
                              hipStream_t stream) {
  const float* x  = (const float*)d_in[0];   // logits (64,1,512,512)
  const float* tg = (const float*)d_in[1];   // target (64,1,512,512)
  uint32_t* ws = (uint32_t*)d_ws;
  float* out = (float*)d_out;

  hipLaunchKernelGGL(k_init, dim3(25),           dim3(256), 0, stream, ws, out);
  hipLaunchKernelGGL(k_main, dim3(BATCH * PBLK), dim3(256), 0, stream, x, tg, ws, out);
}

// Round 16
// 39.432 us; speedup vs baseline: 1.5454x; 1.5454x over previous
//
#include <hip/hip_runtime.h>
#include <cstdint>

static constexpr int BATCH = 64;
static constexpr int NPB   = 512 * 512;   // elements per batch
static constexpr int NFB   = 2048;        // fine fixed bins in sigmoid space [0,1]
static constexpr int PBLK  = 8;           // blocks per batch (512 total)
static constexpr int ELB   = NPB / PBLK;  // 32768 elements per block

// d_ws layout in 32-bit words (~4.2 MB):
static constexpr int W_BMIN = 0;      // 512 floats: per-block min
static constexpr int W_BMAX = 512;    // 512 floats: per-block max
static constexpr int W_T1   = 1024;   // 64 tickets, 32-word (128 B) stride -> [1024,3072)
static constexpr int W_T3   = 3072;   // 1 global leader ticket (padded to 32)
static constexpr int W_IOU  = 3104;   // 64 floats: per-batch IoU
static constexpr int W_PART = 4096;   // 512 x 2048 packed (tot|pos<<16) partial hists

__device__ __forceinline__ float sigmoidf(float v) {  // precise: pmin/pmax only
  if (v >= 0.0f) return 1.0f / (1.0f + expf(-v));
  float e = expf(v);
  return e / (1.0f + e);
}
__device__ __forceinline__ float fsig(float v) {      // fast: per-element binning only
  return __builtin_amdgcn_rcpf(1.0f + __expf(-v));
}
__device__ __forceinline__ uint32_t llc_load(const uint32_t* p) {   // served at LLC
  return __hip_atomic_load(p, __ATOMIC_RELAXED, __HIP_MEMORY_SCOPE_SYSTEM);
}
__device__ __forceinline__ float llc_loadf(const float* p) {
  return __hip_atomic_load(p, __ATOMIC_RELAXED, __HIP_MEMORY_SCOPE_SYSTEM);
}
__device__ __forceinline__ void llc_store(uint32_t* p, uint32_t v) {  // write-through
  __hip_atomic_store(p, v, __ATOMIC_RELAXED, __HIP_MEMORY_SCOPE_SYSTEM);
}
__device__ __forceinline__ void llc_storef(float* p, float v) {
  __hip_atomic_store(p, v, __ATOMIC_RELAXED, __HIP_MEMORY_SCOPE_SYSTEM);
}

// Init: zero tickets only ([W_T1, W_IOU) = 2080 words). 1 block.
__global__ __launch_bounds__(256) void k_init(uint32_t* __restrict__ ws) {
  for (int i = threadIdx.x; i < 2080; i += 256) ws[W_T1 + i] = 0u;
}

// One data pass (R10-proven math) + fused ticket-leader finalize (R8-proven math).
// No spins, no polls: non-leader blocks exit after their ticket.
__global__ __launch_bounds__(256) void k_main(const float* __restrict__ x,
                                              const float* __restrict__ tg,
                                              uint32_t* __restrict__ ws,
                                              float* __restrict__ out) {
  __shared__ uint32_t pool[4096];        // 16 KiB: 2 packed hist replicas -> tot/pos
  __shared__ uint32_t h256[256];
  __shared__ uint32_t scanA[256];
  __shared__ float    scanB[256];
  __shared__ float    scanC[256];
  __shared__ int      scanD[256];
  __shared__ unsigned long long redL[256];
  __shared__ float smn[4], smx[4];
  __shared__ int sFlag, sLast;
  __shared__ float sPmin, sScale, sBinw;
  const int t = threadIdx.x, g = blockIdx.x;
  const int b = g >> 3, blk = g & 7;
  float* wsf = reinterpret_cast<float*>(ws);

#pragma unroll
  for (int q = 0; q < 4; ++q)
    reinterpret_cast<uint4*>(pool)[t + q * 256] = uint4{0u, 0u, 0u, 0u};
  __syncthreads();

  const size_t base = (size_t)b * NPB + (size_t)blk * ELB;
  const float4* px = reinterpret_cast<const float4*>(x + base);
  const float4* pt = reinterpret_cast<const float4*>(tg + base);
  const uint32_t woff = (uint32_t)(t >> 7) << 11;   // wave-pair replica (0 or 2048)

  // ---- phase 1: ONE stream; packed (tot|pos) full-rate hist; min/max ----
  float mn = INFINITY, mx = -INFINITY;
#pragma unroll 4
  for (int i = 0; i < 32; ++i) {
    float4 v = px[i * 256 + t];
    float4 w = pt[i * 256 + t];
    mn = fminf(mn, fminf(fminf(v.x, v.y), fminf(v.z, v.w)));
    mx = fmaxf(mx, fmaxf(fmaxf(v.x, v.y), fmaxf(v.z, v.w)));
#define PUT(a, c) { int idx = (int)(fsig(a) * 2048.0f);                        \
                    idx = idx > 2047 ? 2047 : idx;                             \
                    const uint32_t val = ((c) > 0.5f) ? 0x10001u : 1u;         \
                    (void)__hip_atomic_fetch_add(&pool[woff + idx], val,       \
                        __ATOMIC_RELAXED, __HIP_MEMORY_SCOPE_WORKGROUP); }
    PUT(v.x, w.x) PUT(v.y, w.y) PUT(v.z, w.z) PUT(v.w, w.w)
#undef PUT
  }
  for (int off = 32; off; off >>= 1) {
    mn = fminf(mn, __shfl_down(mn, off));
    mx = fmaxf(mx, __shfl_down(mx, off));
  }
  if ((t & 63) == 0) { smn[t >> 6] = mn; smx[t >> 6] = mx; }
  __syncthreads();                       // LDS atomics + smn/smx complete
  if (t == 0) {
    mn = fminf(fminf(smn[0], smn[1]), fminf(smn[2], smn[3]));
    mx = fmaxf(fmaxf(smx[0], smx[1]), fmaxf(smx[2], smx[3]));
    llc_storef(&wsf[W_BMIN + g], mn);    // publish at LLC (write-through)
    llc_storef(&wsf[W_BMAX + g], mx);
  }
  // flush merged replicas (u16 fields add; per-block count <= 32768) to LLC
  uint32_t* gp = ws + W_PART + (size_t)g * NFB;
#pragma unroll
  for (int q = 0; q < 8; ++q) {
    const int w_ = t + q * 256;
    llc_store(&gp[w_], pool[w_] + pool[w_ + 2048]);
  }
  __syncthreads();                       // all waves drain vmcnt at this barrier
  if (t == 0) {
    asm volatile("s_waitcnt vmcnt(0)" ::: "memory");
    sFlag = (atomicAdd(&ws[W_T1 + b * 32], 1u) == PBLK - 1);
  }
  __syncthreads();
  if (!sFlag) return;                    // non-leaders done (no waiting anywhere)

  // ---- leader (last arriver): merge -> Otsu -> suffix counts -> IoU ----
  // merge 8 packed partials; unpack to tot=pool[k], pos=pool[k+2048] (u32, no ovf)
#pragma unroll
  for (int q = 0; q < 8; ++q) {
    const int k = t + q * 256;
    uint32_t at = 0, ap = 0;
#pragma unroll
    for (int p = 0; p < PBLK; ++p) {
      const uint32_t v = llc_load(&ws[W_PART + (size_t)(b * 8 + p) * NFB + k]);
      at += v & 0xFFFFu;
      ap += v >> 16;
    }
    // safe ordering: k in [0,2047] written before any read of pool[k+2048]? No:
    // stage into registers then write both after a barrier-free pattern:
    scanA[0] = scanA[0];                 // no-op
    pool[k] = at | 0u;                   // tot (overwrites this block's replica A)
    redL[t] = 0ull;                      // init reduce slot (reused later)
    pool[k + 2048] = ap;                 // pos (overwrites replica B)
  }
  h256[t] = 0u;
  float mnv = (t < 8) ? llc_loadf(&wsf[W_BMIN + b * 8 + t]) : INFINITY;
  float mxv = (t < 8) ? llc_loadf(&wsf[W_BMAX + b * 8 + t]) : -INFINITY;
  for (int off = 4; off; off >>= 1) {
    mnv = fminf(mnv, __shfl_down(mnv, off));
    mxv = fmaxf(mxv, __shfl_down(mxv, off));
  }
  if (t == 0) {
    const float pmin = sigmoidf(mnv);
    const float pmax = sigmoidf(mxv);
    const float span = pmax - pmin;
    sPmin = pmin;
    sScale = (span > 0.0f) ? (512.0f / span) : -1.0f;   // negative = degenerate
    sBinw = span * (1.0f / 256.0f);
  }
  __syncthreads();
  const float pmin = sPmin, scale = sScale, binw = sBinw;
  const bool degen = (scale < 0.0f);
#define CIDX(k) ({ const float rep = ((float)(k) + 0.5f) * (1.0f / 2048.0f);  \
                   int ci_ = (int)((rep - pmin) * scale);                     \
                   ci_ = ci_ < 0 ? 0 : (ci_ > 511 ? 511 : ci_); ci_; })
  if (!degen) {
#pragma unroll
    for (int q = 0; q < 8; ++q) {        // fine -> 256-bin via midpoint halfbin map
      const int k = t + q * 256;
      const uint32_t ct = pool[k];
      if (ct) atomicAdd(&h256[CIDX(k) >> 1], ct);
    }
  }
  __syncthreads();
  const uint32_t hk = h256[t];
  const float ck = pmin + ((float)t + 0.5f) * binw;     // centers[t]
  scanA[t] = hk;
  scanB[t] = (float)hk * ck;
  for (int off = 1; off < 256; off <<= 1) {             // Hillis-Steele scans
    __syncthreads();
    uint32_t wp = (t >= off) ? scanA[t - off] : 0u;
    float    sp = (t >= off) ? scanB[t - off] : 0.0f;
    __syncthreads();
    scanA[t] += wp; scanB[t] += sp;
  }
  __syncthreads();
  const uint32_t totW = scanA[255];
  const float totS = scanB[255];
  float vv = -INFINITY;
  if (t < 255 && scanA[t] > 0u && totW > scanA[t]) {
    const float w1f = (float)scanA[t];
    const float w2f = (float)(totW - scanA[t]);
    const float m1 = scanB[t] / w1f;
    const float m2 = (totS - scanB[t]) / w2f;
    const float d = m1 - m2;
    vv = (w1f * w2f) * (d * d);
  }
  scanC[t] = vv; scanD[t] = t;
  for (int s = 128; s; s >>= 1) {        // argmax, first-occurrence tie-break
    __syncthreads();
    if (t < s) {
      const float vb = scanC[t + s]; const int ib = scanD[t + s];
      if (vb > scanC[t] || (vb == scanC[t] && ib < scanD[t])) {
        scanC[t] = vb; scanD[t] = ib;
      }
    }
  }
  __syncthreads();
  const int Jh = degen ? (1 << 20) : (2 * scanD[0] + 1);  // halfbin boundary index
  // suffix counts over fine bins with CIDX(k) >= Jh; nt = sum(pos)
  uint32_t nb = 0, ni = 0, nt = 0;
#pragma unroll
  for (int q = 0; q < 8; ++q) {
    const int k = t + q * 256;
    const uint32_t ct = pool[k], cp = pool[k + 2048];
    nt += cp;
    const int ci = degen ? 0 : CIDX(k);
    if (ci >= Jh) { nb += ct; ni += cp; }
  }
#undef CIDX
  redL[t] = (unsigned long long)nb | ((unsigned long long)ni << 20) |
            ((unsigned long long)nt << 40);
  for (int s = 128; s; s >>= 1) {
    __syncthreads();
    if (t < s) redL[t] += redL[t + s];
  }
  __syncthreads();
  if (t == 0) {
    const unsigned long long P = redL[0];
    const float NB = (float)(uint32_t)(P & 0xFFFFFu);
    const float NI = (float)(uint32_t)((P >> 20) & 0xFFFFFu);
    const float NT = (float)(uint32_t)((P >> 40) & 0xFFFFFu);
    llc_storef(&wsf[W_IOU + b], (NI + 1.0f) / ((NB + NT - NI) + 1.0f));
    asm volatile("s_waitcnt vmcnt(0)" ::: "memory");   // IoU at LLC BEFORE ticket
    sLast = (atomicAdd(&ws[W_T3], 1u) == BATCH - 1);
  }
  __syncthreads();
  if (!sLast) return;                    // all but the final leader done

  // ---- final leader: mean of 64 IoUs -> out[0] (single writer) ----
  float iou = (t < 64) ? llc_loadf(&wsf[W_IOU + t]) : 0.0f;
  if (t < 64) {
    for (int off = 32; off; off >>= 1) iou += __shfl_down(iou, off);
    if (t == 0) out[0] = iou * (1.0f / 64.0f);
  }
}

extern "C" void kernel_launch(void* const* d_in, const int* in_sizes, int n_in,
                              void* d_out, int out_size, void* d_ws, size_t ws_size,
                              hipStream_t stream) {
  const float* x  = (const float*)d_in[0];   // logits (64,1,512,512)
  const float* tg = (const float*)d_in[1];   // target (64,1,512,512)
  uint32_t* ws = (uint32_t*)d_ws;
  float* out = (float*)d_out;

  hipLaunchKernelGGL(k_init, dim3(1),            dim3(256), 0, stream, ws);
  hipLaunchKernelGGL(k_main, dim3(BATCH * PBLK), dim3(256), 0, stream, x, tg, ws, out);
}